// Round 11
// baseline (685.413 us; speedup 1.0000x reference)
//
#include <hip/hip_runtime.h>
#include <hip/hip_bf16.h>
#include <math.h>
#include <stdint.h>

typedef _Float16 f16;
typedef _Float16 half8 __attribute__((ext_vector_type(8)));
typedef float f32x4 __attribute__((ext_vector_type(4)));

#define B_ 16
#define S_ 4096
#define D_ 1024
#define F_ 1024
#define TOK (B_*S_)
#define TB4 256        // token tile (4 waves x 64 private tokens)
#define FB4 32         // f tile
#define NFB4 32        // F_/FB4
#define NT3 32         // D_/32 K-tiles
#define NSV 4          // value-pass S chunks
#define CSV (S_/NSV)   // 1024

// async global->LDS, 16B per lane; lds dest = wave-uniform base + lane*16 (HW)
__device__ __forceinline__ void gload_lds16(const void* g, void* l) {
    __builtin_amdgcn_global_load_lds(
        (__attribute__((address_space(1))) const unsigned int*)(unsigned long long)(uintptr_t)g,
        (__attribute__((address_space(3))) unsigned int*)(unsigned int)(uintptr_t)l,
        16, 0, 0);
}

__device__ __forceinline__ void fma4(float4& a, float s, const float4& wv) {
    a.x += s * wv.x; a.y += s * wv.y; a.z += s * wv.z; a.w += s * wv.w;
}
__device__ __forceinline__ void wtanh4(float4& acc, float pw, const float4& a) {
    acc.x += pw * tanhf(a.x); acc.y += pw * tanhf(a.y);
    acc.z += pw * tanhf(a.z); acc.w += pw * tanhf(a.w);
}

// ---------------- kernel 0a: convert x fp32 -> fp16 ----------------
__global__ void cvt_x(const float* __restrict__ x, f16* __restrict__ xh) {
    size_t i = ((size_t)blockIdx.x * 256 + threadIdx.x) * 8;
    float4 a = *(const float4*)(x + i);
    float4 b = *(const float4*)(x + i + 4);
    half8 h = {(f16)a.x,(f16)a.y,(f16)a.z,(f16)a.w,
               (f16)b.x,(f16)b.y,(f16)b.z,(f16)b.w};
    *(half8*)(xh + i) = h;
}

// ------- kernel 0b: pack Wk,Wq -> MFMA-fragment-major f16 (32-f blocks) -------
// frag gw = ((mat*32+fb)*32 + kt)*2 + n ; lane l holds f = fb*32+n*16+(l&15),
// k = kt*32+(l>>4)*8..+8 (B-operand of mfma_f32_16x16x32_f16), 1KB contiguous.
__global__ void cvt_w2(const float* __restrict__ Wk, const float* __restrict__ Wq,
                       f16* __restrict__ wtf) {
    const int gw   = blockIdx.x * 4 + (threadIdx.x >> 6);   // 0..4095
    const int lane = threadIdx.x & 63;
    const int n = gw & 1, kt = (gw >> 1) & 31, fb = (gw >> 6) & 31, mat = gw >> 11;
    const float* W = mat ? Wq : Wk;
    const int f  = fb * 32 + n * 16 + (lane & 15);
    const int d0 = kt * 32 + (lane >> 4) * 8;
    half8 h;
#pragma unroll
    for (int e = 0; e < 8; ++e) h[e] = (f16)W[(size_t)(d0 + e) * F_ + f];
    *(half8*)(wtf + (size_t)gw * 512 + lane * 8) = h;
}

// ------------- kernel 1: fused Q/K GEMM + tanh + diag-dot partials -------------
// ZERO-BARRIER K-loop: block = 256 tok x 32 f, 4 waves each owning 64 PRIVATE
// tokens. Per wave: private 3-slot LDS X pipeline (gload_lds, depth-2, T2
// swizzle both-sides), W frags global->reg ping-pong (L1/L2-hot), per-wave
// counted vmcnt (12 steady / 8 first / 4 last), NO s_barrier in the loop.
// Epilogue fully wave-local (own tokens, all 32 f) -> direct store.
// T1: XCD chunks of 1024, fb fastest (32 fb reuse each X tile via L2).
__launch_bounds__(256, 3)
__global__ void score_gemm(const f16* __restrict__ xh, const f16* __restrict__ wtf,
                           float* __restrict__ part) {
    __shared__ __align__(16) f16 Xs[4][3][64 * 32];   // per-wave 3 x 4KB = 48KB

    const int hid  = blockIdx.x;
    const int orig = (hid & 7) * 1024 + (hid >> 3);
    const int fb   = orig & 31;                 // FAST: 32 fb per X tile
    const int tok0 = (orig >> 5) * TB4;

    const int t = threadIdx.x, lane = t & 63, w = t >> 6;
    const int wr = w * 64;            // wave's private 64 tokens

    // X staging: 4 gload_lds per tile; inst i, lane l -> row = i*16+(l>>2),
    // quad q = (l&3) ^ ((row>>1)&3)  (pre-swizzled source, linear LDS dest)
    const f16* srcX[4];
#pragma unroll
    for (int i = 0; i < 4; ++i) {
        int row = i * 16 + (lane >> 2);
        int q   = (lane & 3) ^ ((row >> 1) & 3);
        srcX[i] = xh + (size_t)(tok0 + wr + row) * D_ + q * 8;
    }
    f16* ldsbase = &Xs[w][0][0];      // wave-uniform

    // A-fragment read offsets (swizzled read side of the involution)
    int offA[4];
#pragma unroll
    for (int m = 0; m < 4; ++m) {
        int row = m * 16 + (lane & 15);
        int q   = (lane >> 4) ^ ((row >> 1) & 3);
        offA[m] = row * 32 + q * 8;
    }

    // W fragment pointers: gw = ((mat*32+fb)*32+kt)*2+n, 1KB per frag
    const f16* bK = wtf + ((size_t)fb * 32) * 2 * 512 + lane * 8;
    const f16* bQ = bK + (size_t)2048 * 512;   // mat=1 half (+2MB elems/2)

#define STAGE_X(sl, kof) do {                                             \
        char* xb = (char*)(ldsbase + (sl) * 2048);                        \
        _Pragma("unroll")                                                 \
        for (int i_ = 0; i_ < 4; ++i_)                                    \
            gload_lds16(srcX[i_] + (kof), xb + i_ * 1024);                \
    } while (0)

    f32x4 accK[4][2] = {};
    f32x4 accQ[4][2] = {};
    half8 wKf[2][2], wQf[2][2];

    // prologue: W(0) first, then X(0), X(1)  (order matters for vmcnt counts)
#pragma unroll
    for (int n = 0; n < 2; ++n) {
        wKf[0][n] = *(const half8*)(bK + n * 512);
        wQf[0][n] = *(const half8*)(bQ + n * 512);
    }
    STAGE_X(0, 0);
    STAGE_X(1, 32);

#pragma unroll
    for (int kt = 0; kt < NT3; ++kt) {
        const int cur = kt % 3, par = kt & 1, nx = par ^ 1;

        // issue W(kt+1) frag loads (reg ping-pong)
        if (kt < NT3 - 1) {
#pragma unroll
            for (int n = 0; n < 2; ++n) {
                wKf[nx][n] = *(const half8*)(bK + ((size_t)(kt + 1) * 2 + n) * 512);
                wQf[nx][n] = *(const half8*)(bQ + ((size_t)(kt + 1) * 2 + n) * 512);
            }
        }

        // per-wave counted wait: X(kt)'s 4 gload_lds retired (FIFO oldest-first)
        if (kt == 0)            asm volatile("s_waitcnt vmcnt(8)"  ::: "memory");
        else if (kt == NT3 - 1) asm volatile("s_waitcnt vmcnt(4)"  ::: "memory");
        else                    asm volatile("s_waitcnt vmcnt(12)" ::: "memory");

        half8 aF[4];
#pragma unroll
        for (int m = 0; m < 4; ++m)
            aF[m] = *(const half8*)(ldsbase + cur * 2048 + offA[m]);

        __builtin_amdgcn_s_setprio(1);
#pragma unroll
        for (int n = 0; n < 2; ++n)
#pragma unroll
            for (int m = 0; m < 4; ++m) {
                accK[m][n] = __builtin_amdgcn_mfma_f32_16x16x32_f16(aF[m], wKf[par][n], accK[m][n], 0, 0, 0);
                accQ[m][n] = __builtin_amdgcn_mfma_f32_16x16x32_f16(aF[m], wQf[par][n], accQ[m][n], 0, 0, 0);
            }
        __builtin_amdgcn_s_setprio(0);

        // re-stage slot (kt+2)%3 AFTER this tile's MFMAs (ds_reads of the slot
        // being overwritten were lgkm-retired before the MFMAs above)
        if (kt < NT3 - 2) STAGE_X((kt + 2) % 3, (kt + 2) * 32);
    }
#undef STAGE_X

    // epilogue: wave-local. tanh-product, sum over n + lane&15 (f), store own rows.
#pragma unroll
    for (int m = 0; m < 4; ++m) {
        float s[4] = {0.f, 0.f, 0.f, 0.f};
#pragma unroll
        for (int n = 0; n < 2; ++n)
#pragma unroll
            for (int j = 0; j < 4; ++j)
                s[j] += tanhf(accQ[m][n][j]) * tanhf(accK[m][n][j]);
#pragma unroll
        for (int j = 0; j < 4; ++j) {
            s[j] += __shfl_xor(s[j], 1);
            s[j] += __shfl_xor(s[j], 2);
            s[j] += __shfl_xor(s[j], 4);
            s[j] += __shfl_xor(s[j], 8);
        }
        if ((lane & 15) == 0) {
            int g = lane >> 4;
#pragma unroll
            for (int j = 0; j < 4; ++j)
                part[(size_t)fb * TOK + tok0 + wr + m * 16 + g * 4 + j] = s[j];
        }
    }
}

// ------------- kernel 2a: reduce fb partials -> scores[tok] -------------
__global__ void sum_k(const float* __restrict__ part, float* __restrict__ scores) {
    int i = blockIdx.x * 256 + threadIdx.x;
    float s = 0.f;
#pragma unroll
    for (int fb = 0; fb < NFB4; ++fb) s += part[(size_t)fb * TOK + i];
    scores[i] = s;
}

// ------------- kernel 2b: per-batch softmax over S -------------
__global__ void softmax_k(const float* __restrict__ scores, float* __restrict__ out) {
    __shared__ float sc[S_];
    __shared__ float red[256];
    const int b = blockIdx.x, t = threadIdx.x;
    float lmax = -1e30f;
    for (int i = t; i < S_; i += 256) {
        float s = scores[(size_t)b * S_ + i];
        sc[i] = s;
        lmax = fmaxf(lmax, s);
    }
    red[t] = lmax; __syncthreads();
    for (int o = 128; o > 0; o >>= 1) { if (t < o) red[t] = fmaxf(red[t], red[t + o]); __syncthreads(); }
    const float mx = red[0]; __syncthreads();
    float lsum = 0.f;
    for (int i = t; i < S_; i += 256) { float e = expf(sc[i] - mx); sc[i] = e; lsum += e; }
    red[t] = lsum; __syncthreads();
    for (int o = 128; o > 0; o >>= 1) { if (t < o) red[t] += red[t + o]; __syncthreads(); }
    const float inv = 1.0f / red[0];
    for (int i = t; i < S_; i += 256)
        out[(size_t)B_ * F_ + (size_t)b * S_ + i] = sc[i] * inv;
}

// ------------- kernel 3: sparse value pass, NSV chunks, groups of 8 -------------
__launch_bounds__(256)
__global__ void value_k4(const float* __restrict__ x, const float* __restrict__ Wv,
                         const float* __restrict__ p_in, float* __restrict__ vpart) {
    __shared__ __align__(16) float xs[8][D_];   // 32 KB
    __shared__ float ps[CSV];
    __shared__ int   idxs[CSV];
    __shared__ int   wsum[4];
    __shared__ int   rbase_s;
    const int b = blockIdx.x, c = blockIdx.y;
    const int t = threadIdx.x, lane = t & 63, w = t >> 6;
    const int s0 = c * CSV;

    if (t == 0) rbase_s = 0;
    __syncthreads();
#pragma unroll 1
    for (int r = 0; r < 4; ++r) {
        int i = r * 256 + t;
        float p = p_in[(size_t)b * S_ + s0 + i];
        bool flag = p > 1e-7f;
        unsigned long long mask = __ballot(flag);
        if (lane == 0) wsum[w] = __popcll(mask);
        __syncthreads();
        int base = rbase_s;
#pragma unroll
        for (int k = 0; k < 4; ++k) if (k < w) base += wsum[k];
        if (flag) {
            int pos = base + __popcll(mask & ((1ull << lane) - 1ull));
            idxs[pos] = s0 + i;
            ps[pos] = p;
        }
        __syncthreads();
        if (t == 0) rbase_s += wsum[0] + wsum[1] + wsum[2] + wsum[3];
        __syncthreads();
    }
    const int cnt = rbase_s;

    float4 acc = {0.f, 0.f, 0.f, 0.f};
    for (int g = 0; g < cnt; g += 8) {
        __syncthreads();
#pragma unroll
        for (int r = 0; r < 8; ++r) {
            float4 v = {0.f, 0.f, 0.f, 0.f};
            if (g + r < cnt)
                v = ((const float4*)(x + ((size_t)b * S_ + idxs[g + r]) * D_))[t];
            ((float4*)xs[r])[t] = v;
        }
        __syncthreads();
        float4 a[8] = {};
#pragma unroll 2
        for (int dq = 0; dq < D_ / 4; ++dq) {
            const float* wrp = Wv + (size_t)dq * 4 * F_;
            float4 wv0 = ((const float4*)(wrp        ))[t];
            float4 wv1 = ((const float4*)(wrp + F_   ))[t];
            float4 wv2 = ((const float4*)(wrp + 2*F_ ))[t];
            float4 wv3 = ((const float4*)(wrp + 3*F_ ))[t];
#pragma unroll
            for (int r = 0; r < 8; ++r) {
                float4 xr = ((const float4*)xs[r])[dq];
                fma4(a[r], xr.x, wv0); fma4(a[r], xr.y, wv1);
                fma4(a[r], xr.z, wv2); fma4(a[r], xr.w, wv3);
            }
        }
#pragma unroll
        for (int r = 0; r < 8; ++r)
            if (g + r < cnt) wtanh4(acc, ps[g + r], a[r]);
    }
    ((float4*)(vpart + ((size_t)c * B_ + b) * F_))[t] = acc;
}

// ------------- kernel 4: reduce chunk partials -------------
__global__ void value_red(const float* __restrict__ vpart, float* __restrict__ out) {
    int i = blockIdx.x * 256 + threadIdx.x;
    float s = 0.f;
#pragma unroll
    for (int c = 0; c < NSV; ++c) s += vpart[(size_t)c * B_ * F_ + i];
    out[i] = s;
}

extern "C" void kernel_launch(void* const* d_in, const int* in_sizes, int n_in,
                              void* d_out, int out_size, void* d_ws, size_t ws_size,
                              hipStream_t stream) {
    const float* x  = (const float*)d_in[0];
    const float* Wk = (const float*)d_in[1];
    const float* Wq = (const float*)d_in[2];
    const float* Wv = (const float*)d_in[3];
    float* out = (float*)d_out;
    char* ws = (char*)d_ws;

    f16*   xh     = (f16*)ws;                                            // 128 MB
    f16*   wtf    = (f16*)(ws + (size_t)TOK * D_ * 2);                   // 4 MB frag-major W
    float* part   = (float*)(ws + (size_t)TOK * D_ * 2 + 2 * (size_t)D_ * F_ * 2); // 8 MB (32 fb)
    float* scores = part + (size_t)NFB4 * TOK;                           // 256 KB

    cvt_x<<<TOK * D_ / 8 / 256, 256, 0, stream>>>(x, xh);
    cvt_w2<<<1024, 256, 0, stream>>>(Wk, Wq, wtf);
    score_gemm<<<NFB4 * (TOK / TB4), 256, 0, stream>>>(xh, wtf, part);
    sum_k<<<TOK / 256, 256, 0, stream>>>(part, scores);
    softmax_k<<<B_, 256, 0, stream>>>(scores, out);
    float* vpart = part;
    const float* p_in = out + (size_t)B_ * F_;
    value_k4<<<dim3(B_, NSV), 256, 0, stream>>>(x, Wv, p_in, vpart);
    value_red<<<B_ * F_ / 256, 256, 0, stream>>>(vpart, out);
}

// Round 12
// 551.087 us; speedup vs baseline: 1.2437x; 1.2437x over previous
//
#include <hip/hip_runtime.h>
#include <hip/hip_bf16.h>
#include <math.h>
#include <stdint.h>

typedef _Float16 f16;
typedef _Float16 half8 __attribute__((ext_vector_type(8)));
typedef float f32x4 __attribute__((ext_vector_type(4)));

#define B_ 16
#define S_ 4096
#define D_ 1024
#define F_ 1024
#define TOK (B_*S_)
#define TB3 128        // token tile
#define FB3 64         // f tile
#define NFB3 16        // F_/FB3
#define NT3 32         // D_/32 K-tiles
#define NSV 4          // value-pass S chunks
#define CSV (S_/NSV)   // 1024

// async global->LDS, 16B per lane; lds dest = wave-uniform base + lane*16 (HW)
__device__ __forceinline__ void gload_lds16(const void* g, void* l) {
    __builtin_amdgcn_global_load_lds(
        (__attribute__((address_space(1))) const unsigned int*)(unsigned long long)(uintptr_t)g,
        (__attribute__((address_space(3))) unsigned int*)(unsigned int)(uintptr_t)l,
        16, 0, 0);
}

__device__ __forceinline__ void fma2(float2& a, float s, const float2& wv) {
    a.x += s * wv.x; a.y += s * wv.y;
}

// ---------------- kernel 0a: convert x fp32 -> fp16 ----------------
__global__ void cvt_x(const float* __restrict__ x, f16* __restrict__ xh) {
    size_t i = ((size_t)blockIdx.x * 256 + threadIdx.x) * 8;
    float4 a = *(const float4*)(x + i);
    float4 b = *(const float4*)(x + i + 4);
    half8 h = {(f16)a.x,(f16)a.y,(f16)a.z,(f16)a.w,
               (f16)b.x,(f16)b.y,(f16)b.z,(f16)b.w};
    *(half8*)(xh + i) = h;
}

// ------- kernel 0b: pack Wk,Wq (fp32 [D][F]) -> MFMA-fragment-major f16 -------
// frag gw = ((mat*16+fb)*32 + kt)*4 + nblk ; lane l holds f = fb*64+nblk*16+(l&15),
// k = kt*32+(l>>4)*8..+8 (B-operand of mfma_f32_16x16x32_f16), contiguous per wave.
__global__ void cvt_w2(const float* __restrict__ Wk, const float* __restrict__ Wq,
                       f16* __restrict__ wtf) {
    const int gw   = blockIdx.x * 4 + (threadIdx.x >> 6);   // 0..4095
    const int lane = threadIdx.x & 63;
    const int nblk = gw & 3, kt = (gw >> 2) & 31, fb = (gw >> 7) & 15, mat = gw >> 11;
    const float* W = mat ? Wq : Wk;
    const int f  = fb * 64 + nblk * 16 + (lane & 15);
    const int d0 = kt * 32 + (lane >> 4) * 8;
    half8 h;
#pragma unroll
    for (int e = 0; e < 8; ++e) h[e] = (f16)W[(size_t)(d0 + e) * F_ + f];
    *(half8*)(wtf + (size_t)gw * 512 + lane * 8) = h;
}

// ------------- kernel 1: fused Q/K GEMM + tanh + diag-dot partials -------------
// R10-proven config (339us): 128x64 tile, 4 waves, each 64 tok x 32 f both mats.
// X LDS-staged (4 slots, gload_lds, T2 swizzle), W frag-major global->reg
// ping-pong, one s_barrier/tile, compiler-counted waits. T1: fb fastest.
// ONLY change vs R10: launch_bounds min-waves 3 -> 4 (128 regs/wave fits:
// 64 VGPR + 64 acc; LDS 33KB x4 = 132KB < 160KB) -> target 4 blocks/CU.
__launch_bounds__(256, 4)
__global__ void score_gemm(const f16* __restrict__ xh, const f16* __restrict__ wtf,
                           float* __restrict__ part) {
    __shared__ __align__(16) f16 Xs[4][TB3 * 32];   // 4 x 8 KB
    __shared__ float sred[2][TB3];                  // 1 KB

    const int hid  = blockIdx.x;
    const int orig = (hid & 7) * 1024 + (hid >> 3);
    const int fb   = orig & 15;                 // FAST: 16 fb per X tile
    const int tok0 = (orig >> 4) * TB3;         // 64 contiguous tok tiles per XCD

    const int t = threadIdx.x, lane = t & 63, w = t >> 6;
    const int wr = (w >> 1) * 64;     // token offset of wave sub-tile
    const int wc = (w & 1) * 32;      // f offset of wave sub-tile

    // X staging sources, pre-swizzled quad (involution q ^ ((row>>1)&3))
    const int rx0 = t >> 2,         qx0 = (t & 3) ^ ((rx0 >> 1) & 3);
    const int rx1 = (t + 256) >> 2, qx1 = (t & 3) ^ ((rx1 >> 1) & 3);
    const f16* srcX0 = xh + (size_t)(tok0 + rx0) * D_ + qx0 * 8;
    const f16* srcX1 = xh + (size_t)(tok0 + rx1) * D_ + qx1 * 8;
    const int wbase = w * 1024;       // wave-uniform LDS byte base

    // A-fragment read offsets (swizzled read side)
    int offA[4];
#pragma unroll
    for (int m = 0; m < 4; ++m) {
        int row = wr + m * 16 + (lane & 15);
        int q   = (lane >> 4) ^ ((row >> 1) & 3);
        offA[m] = row * 32 + q * 8;
    }

    // W fragment base pointers (per-lane): frag elem off = ((fb*32+kt)*4+nblk)*512
    const f16* bK = wtf + (((size_t)fb * NT3 * 4) + 2 * (w & 1)) * 512 + lane * 8;
    const f16* bQ = bK + (size_t)NFB3 * NT3 * 4 * 512;   // mat=1 half

#define STAGE_X(sl, kof) do {                                         \
        gload_lds16(srcX0 + (kof), (char*)Xs[sl] + wbase);            \
        gload_lds16(srcX1 + (kof), (char*)Xs[sl] + 4096 + wbase);     \
    } while (0)

    f32x4 accK[4][2] = {};
    f32x4 accQ[4][2] = {};
    half8 wKf[2][2], wQf[2][2];

    // prologue: X0,X1,X2 staged, then W(0) frags; vmcnt(8) forces X0;
    // MFMA(0)'s auto-wait on W(0) (newest) drains X1,X2 for iters 1,2.
    STAGE_X(0, 0);
    STAGE_X(1, 32);
    STAGE_X(2, 64);
#pragma unroll
    for (int n = 0; n < 2; ++n) {
        wKf[0][n] = *(const half8*)(bK + n * 512);
        wQf[0][n] = *(const half8*)(bQ + n * 512);
    }
    asm volatile("s_waitcnt vmcnt(8)" ::: "memory");
    __builtin_amdgcn_s_barrier();

#pragma unroll
    for (int kt = 0; kt < NT3; ++kt) {
        const int cur = kt & 3, par = kt & 1, nx = par ^ 1;
        if (kt < NT3 - 1) {
#pragma unroll
            for (int n = 0; n < 2; ++n) {
                wKf[nx][n] = *(const half8*)(bK + ((size_t)(kt + 1) * 4 + n) * 512);
                wQf[nx][n] = *(const half8*)(bQ + ((size_t)(kt + 1) * 4 + n) * 512);
            }
        }
        if (kt < NT3 - 3) STAGE_X((kt + 3) & 3, (kt + 3) * 32);

        half8 aF[4];
#pragma unroll
        for (int m = 0; m < 4; ++m) aF[m] = *(const half8*)(Xs[cur] + offA[m]);
#pragma unroll
        for (int n = 0; n < 2; ++n)
#pragma unroll
            for (int m = 0; m < 4; ++m) {
                accK[m][n] = __builtin_amdgcn_mfma_f32_16x16x32_f16(aF[m], wKf[par][n], accK[m][n], 0, 0, 0);
                accQ[m][n] = __builtin_amdgcn_mfma_f32_16x16x32_f16(aF[m], wQf[par][n], accQ[m][n], 0, 0, 0);
            }
        if (kt < NT3 - 1) __builtin_amdgcn_s_barrier();
    }
#undef STAGE_X

    // epilogue: tanh, product, reduce over f, combine 2 f-wave-cols
#pragma unroll
    for (int m = 0; m < 4; ++m) {
        float s[4] = {0.f, 0.f, 0.f, 0.f};
#pragma unroll
        for (int n = 0; n < 2; ++n)
#pragma unroll
            for (int j = 0; j < 4; ++j)
                s[j] += tanhf(accQ[m][n][j]) * tanhf(accK[m][n][j]);
#pragma unroll
        for (int j = 0; j < 4; ++j) {
            s[j] += __shfl_xor(s[j], 1);
            s[j] += __shfl_xor(s[j], 2);
            s[j] += __shfl_xor(s[j], 4);
            s[j] += __shfl_xor(s[j], 8);
        }
        if ((lane & 15) == 0) {
            int g = lane >> 4;
#pragma unroll
            for (int j = 0; j < 4; ++j)
                sred[w & 1][wr + m * 16 + g * 4 + j] = s[j];
        }
    }
    __syncthreads();
    if (t < TB3)
        part[(size_t)fb * TOK + tok0 + t] = sred[0][t] + sred[1][t];
}

// ------------- kernel 2a: reduce fb partials -> scores[tok] -------------
__global__ void sum_k(const float* __restrict__ part, float* __restrict__ scores) {
    int i = blockIdx.x * 256 + threadIdx.x;
    float s = 0.f;
#pragma unroll
    for (int fb = 0; fb < NFB3; ++fb) s += part[(size_t)fb * TOK + i];
    scores[i] = s;
}

// ------------- kernel 2b: per-batch softmax over S -------------
__global__ void softmax_k(const float* __restrict__ scores, float* __restrict__ out) {
    __shared__ float sc[S_];
    __shared__ float red[256];
    const int b = blockIdx.x, t = threadIdx.x;
    float lmax = -1e30f;
    for (int i = t; i < S_; i += 256) {
        float s = scores[(size_t)b * S_ + i];
        sc[i] = s;
        lmax = fmaxf(lmax, s);
    }
    red[t] = lmax; __syncthreads();
    for (int o = 128; o > 0; o >>= 1) { if (t < o) red[t] = fmaxf(red[t], red[t + o]); __syncthreads(); }
    const float mx = red[0]; __syncthreads();
    float lsum = 0.f;
    for (int i = t; i < S_; i += 256) { float e = expf(sc[i] - mx); sc[i] = e; lsum += e; }
    red[t] = lsum; __syncthreads();
    for (int o = 128; o > 0; o >>= 1) { if (t < o) red[t] += red[t + o]; __syncthreads(); }
    const float inv = 1.0f / red[0];
    for (int i = t; i < S_; i += 256)
        out[(size_t)B_ * F_ + (size_t)b * S_ + i] = sc[i] * inv;
}

// --- kernel 3: sparse value pass, 512 threads, thread owns 2 f-cols (float2) ---
// grid (B_, NSV); groups of 8 tokens with a 4-token fast path (typical cnt~4).
__launch_bounds__(512)
__global__ void value_k5(const float* __restrict__ x, const float* __restrict__ Wv,
                         const float* __restrict__ p_in, float* __restrict__ vpart) {
    __shared__ __align__(16) float xs[8][D_];   // 32 KB
    __shared__ float ps[CSV];
    __shared__ int   idxs[CSV];
    __shared__ int   wsum[8];
    __shared__ int   rbase_s;
    const int b = blockIdx.x, c = blockIdx.y;
    const int t = threadIdx.x, lane = t & 63, w = t >> 6;   // w 0..7
    const int s0 = c * CSV;

    if (t == 0) rbase_s = 0;
    __syncthreads();
    // deterministic parallel compaction, 2 rounds of 512
#pragma unroll 1
    for (int r = 0; r < 2; ++r) {
        int i = r * 512 + t;
        float p = p_in[(size_t)b * S_ + s0 + i];
        bool flag = p > 1e-7f;
        unsigned long long mask = __ballot(flag);
        if (lane == 0) wsum[w] = __popcll(mask);
        __syncthreads();
        int base = rbase_s;
#pragma unroll
        for (int k = 0; k < 8; ++k) if (k < w) base += wsum[k];
        if (flag) {
            int pos = base + __popcll(mask & ((1ull << lane) - 1ull));
            idxs[pos] = s0 + i;
            ps[pos] = p;
        }
        __syncthreads();
        if (t == 0) {
            int sum = 0;
#pragma unroll
            for (int k = 0; k < 8; ++k) sum += wsum[k];
            rbase_s += sum;
        }
        __syncthreads();
    }
    const int cnt = rbase_s;

    float2 acc = {0.f, 0.f};
    for (int g = 0; g < cnt; g += 8) {
        __syncthreads();
        const int ng = cnt - g;
#pragma unroll
        for (int r = 0; r < 8; ++r) {
            float2 v = {0.f, 0.f};
            if (r < ng)
                v = ((const float2*)(x + ((size_t)b * S_ + idxs[g + r]) * D_))[t];
            ((float2*)xs[r])[t] = v;          // full 4KB row per r (zero-padded)
        }
        __syncthreads();
        if (ng >= 5) {
            float2 a[8] = {};
#pragma unroll 2
            for (int dq = 0; dq < D_ / 4; ++dq) {
                const float* wrp = Wv + (size_t)dq * 4 * F_ + 2 * t;
                float2 wv0 = *(const float2*)(wrp         );
                float2 wv1 = *(const float2*)(wrp + F_    );
                float2 wv2 = *(const float2*)(wrp + 2 * F_);
                float2 wv3 = *(const float2*)(wrp + 3 * F_);
#pragma unroll
                for (int r = 0; r < 8; ++r) {
                    float4 xr = ((const float4*)xs[r])[dq];
                    fma2(a[r], xr.x, wv0); fma2(a[r], xr.y, wv1);
                    fma2(a[r], xr.z, wv2); fma2(a[r], xr.w, wv3);
                }
            }
#pragma unroll
            for (int r = 0; r < 8; ++r)
                if (g + r < cnt) {
                    float pw = ps[g + r];
                    acc.x += pw * tanhf(a[r].x);
                    acc.y += pw * tanhf(a[r].y);
                }
        } else {
            float2 a[4] = {};
#pragma unroll 2
            for (int dq = 0; dq < D_ / 4; ++dq) {
                const float* wrp = Wv + (size_t)dq * 4 * F_ + 2 * t;
                float2 wv0 = *(const float2*)(wrp         );
                float2 wv1 = *(const float2*)(wrp + F_    );
                float2 wv2 = *(const float2*)(wrp + 2 * F_);
                float2 wv3 = *(const float2*)(wrp + 3 * F_);
#pragma unroll
                for (int r = 0; r < 4; ++r) {
                    float4 xr = ((const float4*)xs[r])[dq];
                    fma2(a[r], xr.x, wv0); fma2(a[r], xr.y, wv1);
                    fma2(a[r], xr.z, wv2); fma2(a[r], xr.w, wv3);
                }
            }
#pragma unroll
            for (int r = 0; r < 4; ++r)
                if (g + r < cnt) {
                    float pw = ps[g + r];
                    acc.x += pw * tanhf(a[r].x);
                    acc.y += pw * tanhf(a[r].y);
                }
        }
    }
    ((float2*)(vpart + ((size_t)c * B_ + b) * F_))[t] = acc;
}

// ------------- kernel 4: reduce chunk partials -------------
__global__ void value_red(const float* __restrict__ vpart, float* __restrict__ out) {
    int i = blockIdx.x * 256 + threadIdx.x;
    float s = 0.f;
#pragma unroll
    for (int c = 0; c < NSV; ++c) s += vpart[(size_t)c * B_ * F_ + i];
    out[i] = s;
}

extern "C" void kernel_launch(void* const* d_in, const int* in_sizes, int n_in,
                              void* d_out, int out_size, void* d_ws, size_t ws_size,
                              hipStream_t stream) {
    const float* x  = (const float*)d_in[0];
    const float* Wk = (const float*)d_in[1];
    const float* Wq = (const float*)d_in[2];
    const float* Wv = (const float*)d_in[3];
    float* out = (float*)d_out;
    char* ws = (char*)d_ws;

    f16*   xh     = (f16*)ws;                                            // 128 MB
    f16*   wtf    = (f16*)(ws + (size_t)TOK * D_ * 2);                   // 4 MB frag-major W
    float* part   = (float*)(ws + (size_t)TOK * D_ * 2 + 2 * (size_t)D_ * F_ * 2); // 4 MB
    float* scores = part + (size_t)NFB3 * TOK;                           // 256 KB

    cvt_x<<<TOK * D_ / 8 / 256, 256, 0, stream>>>(x, xh);
    cvt_w2<<<1024, 256, 0, stream>>>(Wk, Wq, wtf);
    score_gemm<<<NFB3 * (TOK / TB3), 256, 0, stream>>>(xh, wtf, part);
    sum_k<<<TOK / 256, 256, 0, stream>>>(part, scores);
    softmax_k<<<B_, 256, 0, stream>>>(scores, out);
    float* vpart = part;
    const float* p_in = out + (size_t)B_ * F_;
    value_k5<<<dim3(B_, NSV), 512, 0, stream>>>(x, Wv, p_in, vpart);
    value_red<<<B_ * F_ / 256, 256, 0, stream>>>(vpart, out);
}